// Round 3
// baseline (163.568 us; speedup 1.0000x reference)
//
#include <hip/hip_runtime.h>

// Problem constants (match reference)
constexpr int P      = 8;
constexpr int B      = 160;
constexpr int T      = 32;
constexpr int MD     = 8;
constexpr int MA     = 8;
constexpr int ND     = 6;
constexpr int NA     = 6;
constexpr int NBT    = 20;
constexpr int K      = 11;
constexpr int MIN_SEP = 4;
constexpr int NPAIR  = ND * NA;        // 36
constexpr int PB     = P * B;          // 1280
constexpr int NPAIRS = P * B * B;      // 204800
constexpr int NTHR   = NPAIRS * MD;    // 1,638,400 threads (6400 blocks x 256)

// ---------------------------------------------------------------------------
// Phase 1: resolve block_type -> (donor/acceptor index -> coord) gathers ONCE
// per (p, b), packing float4{x, y, z, type_as_int_bits} into workspace.
// ---------------------------------------------------------------------------
__global__ __launch_bounds__(256) void pack_kernel(
    const float* __restrict__ coords,      // (P, B*T, 3)
    const int*   __restrict__ block_type,  // (P, B)
    const int*   __restrict__ n_donH,
    const int*   __restrict__ donH_inds,   // (NBT, MD)
    const int*   __restrict__ donH_type,
    const int*   __restrict__ n_acc,
    const int*   __restrict__ acc_inds,    // (NBT, MA)
    const int*   __restrict__ acc_type,
    float4*      __restrict__ wdon,        // (PB, MD)
    float4*      __restrict__ wacc,        // (PB, MA)
    int2*        __restrict__ wcnt)        // (PB): {nH, nAc}
{
    const int idx  = blockIdx.x * 256 + threadIdx.x;   // < PB*16
    const int slot = idx & 15;
    const int pb   = idx >> 4;
    const int p    = pb / B;
    const int b    = pb - p * B;
    const int bt   = block_type[pb];
    const float* cb = coords + ((size_t)p * B * T + (size_t)b * T) * 3;

    if (slot < MD) {
        const int ai = donH_inds[bt * MD + slot];
        const int ty = donH_type[bt * MD + slot];
        const float* c = cb + ai * 3;
        wdon[pb * MD + slot] = make_float4(c[0], c[1], c[2], __int_as_float(ty * NA));
        if (slot == 0) wcnt[pb] = make_int2(n_donH[bt], n_acc[bt]);
    } else {
        const int s  = slot - MD;
        const int ai = acc_inds[bt * MA + s];
        const int ty = acc_type[bt * MA + s];
        const float* c = cb + ai * 3;
        wacc[pb * MA + s] = make_float4(c[0], c[1], c[2], __int_as_float(ty));
    }
}

// ---------------------------------------------------------------------------
// Phase 2: thread per (p, b1, b2, h) -- 25600 waves (100/CU) so L2/LDS
// latency is hidden by TLP. Each 256-thread block covers exactly one (p,b1)
// and 32 consecutive b2 (B*MD == 5*256), so p/b1/nH are block-uniform.
// ---------------------------------------------------------------------------
__global__ __launch_bounds__(256) void score_kernel(
    const float4* __restrict__ wdon,
    const float4* __restrict__ wacc,
    const int2*   __restrict__ wcnt,
    const int*    __restrict__ min_bond_sep,  // (P, B, B)
    const float*  __restrict__ pair_params,   // (ND, NA, 3)
    const float*  __restrict__ pair_poly,     // (ND, NA, K)
    const float*  __restrict__ global_params, // (1, 3)
    float*        __restrict__ out)           // (P,)
{
    __shared__ float2 s_mm[NPAIR];      // (dmin^2, dmax^2)
    __shared__ float  s_w[NPAIR];
    __shared__ float  s_poly[NPAIR][K];
    __shared__ float  s_red[4];

    if (threadIdx.x < NPAIR) {
        const int i = threadIdx.x;
        const float dmin = pair_params[i * 3 + 0];
        const float dmax = pair_params[i * 3 + 1];
        s_mm[i] = make_float2(dmin * dmin, dmax * dmax);
        s_w[i]  = pair_params[i * 3 + 2];
    }
    for (int i = threadIdx.x; i < NPAIR * K; i += 256)
        s_poly[i / K][i % K] = pair_poly[i];
    __syncthreads();

    const int idx     = blockIdx.x * 256 + threadIdx.x;   // < NTHR
    const int h       = idx & 7;
    const int pairidx = idx >> 3;                          // p*B*B + b1*B + b2
    const int p       = pairidx / (B * B);                 // block-uniform
    const int r       = pairidx - p * (B * B);
    const int b1      = r / B;                             // block-uniform
    const int b2      = r - b1 * B;

    float acc = 0.f;
    const int sep = min_bond_sep[pairidx];

    if ((b1 != b2) && (sep >= MIN_SEP)) {
        const int pb1 = p * B + b1;
        const int pb2 = p * B + b2;
        const int nH  = wcnt[pb1].x;                       // block-uniform
        if (h < nH) {
            const int nAc = wcnt[pb2].y;
            const float4  D  = wdon[pb1 * MD + h];         // 128B/8 lanes, hot
            const float4* ap = wacc + pb2 * MA;
            const int drow = __float_as_int(D.w);

            float4 A[MA];
            #pragma unroll
            for (int a = 0; a < MA; ++a) A[a] = ap[a];     // 8 independent loads

            #pragma unroll
            for (int a = 0; a < MA; ++a) {
                if (a < nAc) {
                    const float dx = D.x - A[a].x;
                    const float dy = D.y - A[a].y;
                    const float dz = D.z - A[a].z;
                    const float d2 = fmaf(dx, dx, fmaf(dy, dy, fmaf(dz, dz, 1e-12f)));
                    // conservative prefilter: dmin^2 >= 1.0, dmax^2 <= 16.0
                    if (d2 >= 0.95f && d2 <= 16.2f) {
                        const int pi = drow + __float_as_int(A[a].w);
                        const float2 mm = s_mm[pi];
                        if (d2 >= mm.x && d2 <= mm.y) {
                            const float d = sqrtf(d2);
                            const float* cf = s_poly[pi];
                            float E = cf[0];
                            #pragma unroll
                            for (int k = 1; k < K; ++k)
                                E = fmaf(E, d, cf[k]);
                            acc = fmaf(s_w[pi], E, acc);
                        }
                    }
                }
            }
            acc *= global_params[0];
        }
    }

    // wave-64 shuffle reduce, then block reduce, then ONE atomic per block.
    #pragma unroll
    for (int off = 32; off; off >>= 1)
        acc += __shfl_down(acc, off, 64);
    if ((threadIdx.x & 63) == 0)
        s_red[threadIdx.x >> 6] = acc;
    __syncthreads();
    if (threadIdx.x == 0)
        atomicAdd(&out[p], s_red[0] + s_red[1] + s_red[2] + s_red[3]);
}

extern "C" void kernel_launch(void* const* d_in, const int* in_sizes, int n_in,
                              void* d_out, int out_size, void* d_ws, size_t ws_size,
                              hipStream_t stream) {
    const float* coords        = (const float*)d_in[0];
    const float* pair_params   = (const float*)d_in[1];
    const float* pair_poly     = (const float*)d_in[2];
    const float* global_params = (const float*)d_in[3];
    const int*   block_type    = (const int*)d_in[4];
    const int*   min_bond_sep  = (const int*)d_in[5];
    const int*   n_donH        = (const int*)d_in[6];
    const int*   donH_inds     = (const int*)d_in[7];
    const int*   donH_type     = (const int*)d_in[8];
    const int*   n_acc         = (const int*)d_in[9];
    const int*   acc_inds      = (const int*)d_in[10];
    const int*   acc_type      = (const int*)d_in[11];
    float* out = (float*)d_out;

    // Workspace layout (~330 KB)
    float4* wdon = (float4*)d_ws;                 // PB*MD*16 B
    float4* wacc = wdon + PB * MD;                // PB*MA*16 B
    int2*   wcnt = (int2*)(wacc + PB * MA);       // PB*8 B

    // harness poisons d_out with 0xAA before every timed launch
    hipMemsetAsync(out, 0, P * sizeof(float), stream);

    pack_kernel<<<(PB * 16) / 256, 256, 0, stream>>>(
        coords, block_type, n_donH, donH_inds, donH_type,
        n_acc, acc_inds, acc_type, wdon, wacc, wcnt);

    score_kernel<<<NTHR / 256, 256, 0, stream>>>(
        wdon, wacc, wcnt, min_bond_sep,
        pair_params, pair_poly, global_params, out);
}

// Round 4
// 95.556 us; speedup vs baseline: 1.7118x; 1.7118x over previous
//
#include <hip/hip_runtime.h>

// Problem constants (match reference)
constexpr int P      = 8;
constexpr int B      = 160;
constexpr int T      = 32;
constexpr int MD     = 8;
constexpr int MA     = 8;
constexpr int ND     = 6;
constexpr int NA     = 6;
constexpr int NBT    = 20;
constexpr int K      = 11;
constexpr int MIN_SEP = 4;
constexpr int NPAIR  = ND * NA;        // 36
constexpr int PB     = P * B;          // 1280
constexpr int NPAIRS = P * B * B;      // 204800
constexpr int NTHR   = NPAIRS * MD;    // 1,638,400 threads
constexpr int NBLK   = NTHR / 256;     // 6400 score blocks
constexpr int BLK_PER_P = NBLK / P;    // 800

// ---------------------------------------------------------------------------
// Phase 1: resolve block_type -> (donor/acceptor index -> coord) gathers ONCE
// per (p, b), packing float4{x, y, z, type_as_int_bits} into workspace.
// ---------------------------------------------------------------------------
__global__ __launch_bounds__(256) void pack_kernel(
    const float* __restrict__ coords,      // (P, B*T, 3)
    const int*   __restrict__ block_type,  // (P, B)
    const int*   __restrict__ n_donH,
    const int*   __restrict__ donH_inds,   // (NBT, MD)
    const int*   __restrict__ donH_type,
    const int*   __restrict__ n_acc,
    const int*   __restrict__ acc_inds,    // (NBT, MA)
    const int*   __restrict__ acc_type,
    float4*      __restrict__ wdon,        // (PB, MD)
    float4*      __restrict__ wacc,        // (PB, MA)
    int2*        __restrict__ wcnt)        // (PB): {nH, nAc}
{
    const int idx  = blockIdx.x * 256 + threadIdx.x;   // < PB*16
    const int slot = idx & 15;
    const int pb   = idx >> 4;
    const int p    = pb / B;
    const int b    = pb - p * B;
    const int bt   = block_type[pb];
    const float* cb = coords + ((size_t)p * B * T + (size_t)b * T) * 3;

    if (slot < MD) {
        const int ai = donH_inds[bt * MD + slot];
        const int ty = donH_type[bt * MD + slot];
        const float* c = cb + ai * 3;
        wdon[pb * MD + slot] = make_float4(c[0], c[1], c[2], __int_as_float(ty * NA));
        if (slot == 0) wcnt[pb] = make_int2(n_donH[bt], n_acc[bt]);
    } else {
        const int s  = slot - MD;
        const int ai = acc_inds[bt * MA + s];
        const int ty = acc_type[bt * MA + s];
        const float* c = cb + ai * 3;
        wacc[pb * MA + s] = make_float4(c[0], c[1], c[2], __int_as_float(ty));
    }
}

// ---------------------------------------------------------------------------
// Phase 2: thread per (p, b1, b2, h). NO global atomics — each block writes
// its partial sum to an exclusive slot in `partials`.
// ---------------------------------------------------------------------------
__global__ __launch_bounds__(256) void score_kernel(
    const float4* __restrict__ wdon,
    const float4* __restrict__ wacc,
    const int2*   __restrict__ wcnt,
    const int*    __restrict__ min_bond_sep,  // (P, B, B)
    const float*  __restrict__ pair_params,   // (ND, NA, 3)
    const float*  __restrict__ pair_poly,     // (ND, NA, K)
    const float*  __restrict__ global_params, // (1, 3)
    float*        __restrict__ partials)      // (NBLK,) == (P, 800)
{
    __shared__ float2 s_mm[NPAIR];      // (dmin^2, dmax^2)
    __shared__ float  s_w[NPAIR];
    __shared__ float  s_poly[NPAIR][K];
    __shared__ float  s_red[4];

    if (threadIdx.x < NPAIR) {
        const int i = threadIdx.x;
        const float dmin = pair_params[i * 3 + 0];
        const float dmax = pair_params[i * 3 + 1];
        s_mm[i] = make_float2(dmin * dmin, dmax * dmax);
        s_w[i]  = pair_params[i * 3 + 2];
    }
    for (int i = threadIdx.x; i < NPAIR * K; i += 256)
        s_poly[i / K][i % K] = pair_poly[i];
    __syncthreads();

    const int idx     = blockIdx.x * 256 + threadIdx.x;   // < NTHR
    const int h       = idx & 7;
    const int pairidx = idx >> 3;                          // p*B*B + b1*B + b2
    const int p       = pairidx / (B * B);                 // block-uniform
    const int r       = pairidx - p * (B * B);
    const int b1      = r / B;                             // block-uniform
    const int b2      = r - b1 * B;

    float acc = 0.f;
    const int sep = min_bond_sep[pairidx];

    if ((b1 != b2) && (sep >= MIN_SEP)) {
        const int pb1 = p * B + b1;
        const int pb2 = p * B + b2;
        const int nH  = wcnt[pb1].x;                       // block-uniform
        if (h < nH) {
            const int nAc = wcnt[pb2].y;
            const float4  D  = wdon[pb1 * MD + h];         // hot line per block
            const float4* ap = wacc + pb2 * MA;
            const int drow = __float_as_int(D.w);

            float4 A[MA];
            #pragma unroll
            for (int a = 0; a < MA; ++a) A[a] = ap[a];     // independent loads

            #pragma unroll
            for (int a = 0; a < MA; ++a) {
                if (a < nAc) {
                    const float dx = D.x - A[a].x;
                    const float dy = D.y - A[a].y;
                    const float dz = D.z - A[a].z;
                    const float d2 = fmaf(dx, dx, fmaf(dy, dy, fmaf(dz, dz, 1e-12f)));
                    // conservative prefilter: dmin^2 >= 1.0, dmax^2 <= 16.0
                    if (d2 >= 0.95f && d2 <= 16.2f) {
                        const int pi = drow + __float_as_int(A[a].w);
                        const float2 mm = s_mm[pi];
                        if (d2 >= mm.x && d2 <= mm.y) {
                            const float d = sqrtf(d2);
                            const float* cf = s_poly[pi];
                            float E = cf[0];
                            #pragma unroll
                            for (int k = 1; k < K; ++k)
                                E = fmaf(E, d, cf[k]);
                            acc = fmaf(s_w[pi], E, acc);
                        }
                    }
                }
            }
            acc *= global_params[0];
        }
    }

    // wave-64 shuffle reduce -> LDS block reduce -> ONE plain store per block.
    #pragma unroll
    for (int off = 32; off; off >>= 1)
        acc += __shfl_down(acc, off, 64);
    if ((threadIdx.x & 63) == 0)
        s_red[threadIdx.x >> 6] = acc;
    __syncthreads();
    if (threadIdx.x == 0)
        partials[blockIdx.x] = s_red[0] + s_red[1] + s_red[2] + s_red[3];
}

// ---------------------------------------------------------------------------
// Phase 3: 8 blocks, block p exclusively reduces partials[p*800 .. p*800+800)
// into out[p]. No atomics anywhere.
// ---------------------------------------------------------------------------
__global__ __launch_bounds__(256) void reduce_kernel(
    const float* __restrict__ partials,   // (P, BLK_PER_P)
    float*       __restrict__ out)        // (P,)
{
    __shared__ float s_red[4];
    const int p = blockIdx.x;
    float acc = 0.f;
    for (int i = threadIdx.x; i < BLK_PER_P; i += 256)
        acc += partials[p * BLK_PER_P + i];
    #pragma unroll
    for (int off = 32; off; off >>= 1)
        acc += __shfl_down(acc, off, 64);
    if ((threadIdx.x & 63) == 0)
        s_red[threadIdx.x >> 6] = acc;
    __syncthreads();
    if (threadIdx.x == 0)
        out[p] = s_red[0] + s_red[1] + s_red[2] + s_red[3];
}

extern "C" void kernel_launch(void* const* d_in, const int* in_sizes, int n_in,
                              void* d_out, int out_size, void* d_ws, size_t ws_size,
                              hipStream_t stream) {
    const float* coords        = (const float*)d_in[0];
    const float* pair_params   = (const float*)d_in[1];
    const float* pair_poly     = (const float*)d_in[2];
    const float* global_params = (const float*)d_in[3];
    const int*   block_type    = (const int*)d_in[4];
    const int*   min_bond_sep  = (const int*)d_in[5];
    const int*   n_donH        = (const int*)d_in[6];
    const int*   donH_inds     = (const int*)d_in[7];
    const int*   donH_type     = (const int*)d_in[8];
    const int*   n_acc         = (const int*)d_in[9];
    const int*   acc_inds      = (const int*)d_in[10];
    const int*   acc_type      = (const int*)d_in[11];
    float* out = (float*)d_out;

    // Workspace layout (~356 KB)
    float4* wdon     = (float4*)d_ws;               // PB*MD*16 B = 160 KB
    float4* wacc     = wdon + PB * MD;              // PB*MA*16 B = 160 KB
    int2*   wcnt     = (int2*)(wacc + PB * MA);     // PB*8 B     = 10 KB
    float*  partials = (float*)(wcnt + PB);         // NBLK*4 B   = 25.6 KB

    pack_kernel<<<(PB * 16) / 256, 256, 0, stream>>>(
        coords, block_type, n_donH, donH_inds, donH_type,
        n_acc, acc_inds, acc_type, wdon, wacc, wcnt);

    score_kernel<<<NBLK, 256, 0, stream>>>(
        wdon, wacc, wcnt, min_bond_sep,
        pair_params, pair_poly, global_params, partials);

    reduce_kernel<<<P, 256, 0, stream>>>(partials, out);
}

// Round 5
// 90.717 us; speedup vs baseline: 1.8031x; 1.0533x over previous
//
#include <hip/hip_runtime.h>

// Problem constants (match reference)
constexpr int P      = 8;
constexpr int B      = 160;
constexpr int T      = 32;
constexpr int MD     = 8;
constexpr int MA     = 8;
constexpr int ND     = 6;
constexpr int NA     = 6;
constexpr int NBT    = 20;
constexpr int K      = 11;
constexpr int MIN_SEP = 4;
constexpr int NPAIR  = ND * NA;        // 36
constexpr int PB     = P * B;          // 1280
constexpr int NPAIRS = P * B * B;      // 204800
constexpr int NTHR   = NPAIRS * MD;    // 1,638,400 logical threads
constexpr int CHUNK  = 4;              // tiles per score block
constexpr int NBLK_SC = NTHR / 256 / CHUNK;   // 1600 score blocks
constexpr int RED_PER_P = NBLK_SC / P;        // 200 partials per pose

// ---------------------------------------------------------------------------
// Phase 1: resolve block_type -> (donor/acceptor index -> coord) gathers ONCE
// per (p, b), packing float4{x, y, z, type_as_int_bits} into workspace.
// ---------------------------------------------------------------------------
__global__ __launch_bounds__(256) void pack_kernel(
    const float* __restrict__ coords,      // (P, B*T, 3)
    const int*   __restrict__ block_type,  // (P, B)
    const int*   __restrict__ n_donH,
    const int*   __restrict__ donH_inds,   // (NBT, MD)
    const int*   __restrict__ donH_type,
    const int*   __restrict__ n_acc,
    const int*   __restrict__ acc_inds,    // (NBT, MA)
    const int*   __restrict__ acc_type,
    float4*      __restrict__ wdon,        // (PB, MD)
    float4*      __restrict__ wacc,        // (PB, MA)
    int2*        __restrict__ wcnt)        // (PB): {nH, nAc}
{
    const int idx  = blockIdx.x * 256 + threadIdx.x;   // < PB*16
    const int slot = idx & 15;
    const int pb   = idx >> 4;
    const int p    = pb / B;
    const int b    = pb - p * B;
    const int bt   = block_type[pb];
    const float* cb = coords + ((size_t)p * B * T + (size_t)b * T) * 3;

    if (slot < MD) {
        const int ai = donH_inds[bt * MD + slot];
        const int ty = donH_type[bt * MD + slot];
        const float* c = cb + ai * 3;
        wdon[pb * MD + slot] = make_float4(c[0], c[1], c[2], __int_as_float(ty * NA));
        if (slot == 0) wcnt[pb] = make_int2(n_donH[bt], n_acc[bt]);
    } else {
        const int s  = slot - MD;
        const int ai = acc_inds[bt * MA + s];
        const int ty = acc_type[bt * MA + s];
        const float* c = cb + ai * 3;
        wacc[pb * MA + s] = make_float4(c[0], c[1], c[2], __int_as_float(ty));
    }
}

// ---------------------------------------------------------------------------
// Phase 2: logical thread per (p, b1, b2, h); each 256-thread block processes
// CHUNK=4 consecutive tiles so the LDS table staging is amortized 4x.
// No global atomics — one plain partial store per block.
// ---------------------------------------------------------------------------
__global__ __launch_bounds__(256) void score_kernel(
    const float4* __restrict__ wdon,
    const float4* __restrict__ wacc,
    const int2*   __restrict__ wcnt,
    const int*    __restrict__ min_bond_sep,  // (P, B, B)
    const float*  __restrict__ pair_params,   // (ND, NA, 3)
    const float*  __restrict__ pair_poly,     // (ND, NA, K)
    float*        __restrict__ partials)      // (NBLK_SC,) == (P, 200)
{
    __shared__ float2 s_mm[NPAIR];      // (dmin^2, dmax^2)
    __shared__ float  s_w[NPAIR];
    __shared__ float  s_poly[NPAIR][K];
    __shared__ float  s_red[4];

    if (threadIdx.x < NPAIR) {
        const int i = threadIdx.x;
        const float dmin = pair_params[i * 3 + 0];
        const float dmax = pair_params[i * 3 + 1];
        s_mm[i] = make_float2(dmin * dmin, dmax * dmax);
        s_w[i]  = pair_params[i * 3 + 2];
    }
    for (int i = threadIdx.x; i < NPAIR * K; i += 256)
        s_poly[i / K][i % K] = pair_poly[i];
    __syncthreads();

    float acc = 0.f;

    #pragma unroll
    for (int c = 0; c < CHUNK; ++c) {
        const int idx     = (blockIdx.x * CHUNK + c) * 256 + threadIdx.x;
        const int h       = idx & 7;
        const int pairidx = idx >> 3;                      // p*B*B + b1*B + b2
        const int p       = pairidx / (B * B);             // block-uniform
        const int r       = pairidx - p * (B * B);
        const int b1      = r / B;
        const int b2      = r - b1 * B;

        const int sep = min_bond_sep[pairidx];
        if ((b1 != b2) && (sep >= MIN_SEP)) {
            const int pb1 = p * B + b1;
            const int pb2 = p * B + b2;
            const int nH  = wcnt[pb1].x;
            if (h < nH) {
                const int nAc = wcnt[pb2].y;
                const float4  D  = wdon[pb1 * MD + h];
                const float4* ap = wacc + pb2 * MA;
                const int drow = __float_as_int(D.w);

                float4 A[MA];
                #pragma unroll
                for (int a = 0; a < MA; ++a) A[a] = ap[a];   // independent loads

                #pragma unroll
                for (int a = 0; a < MA; ++a) {
                    if (a < nAc) {
                        const float dx = D.x - A[a].x;
                        const float dy = D.y - A[a].y;
                        const float dz = D.z - A[a].z;
                        const float d2 = fmaf(dx, dx, fmaf(dy, dy, fmaf(dz, dz, 1e-12f)));
                        // conservative prefilter: dmin^2 >= 1.0, dmax^2 <= 16.0
                        if (d2 >= 0.95f && d2 <= 16.2f) {
                            const int pi = drow + __float_as_int(A[a].w);
                            const float2 mm = s_mm[pi];
                            if (d2 >= mm.x && d2 <= mm.y) {
                                const float d = sqrtf(d2);
                                const float* cf = s_poly[pi];
                                float E = cf[0];
                                #pragma unroll
                                for (int k = 1; k < K; ++k)
                                    E = fmaf(E, d, cf[k]);
                                acc = fmaf(s_w[pi], E, acc);
                            }
                        }
                    }
                }
            }
        }
    }

    // wave-64 shuffle reduce -> LDS block reduce -> ONE plain store per block.
    #pragma unroll
    for (int off = 32; off; off >>= 1)
        acc += __shfl_down(acc, off, 64);
    if ((threadIdx.x & 63) == 0)
        s_red[threadIdx.x >> 6] = acc;
    __syncthreads();
    if (threadIdx.x == 0)
        partials[blockIdx.x] = s_red[0] + s_red[1] + s_red[2] + s_red[3];
}

// ---------------------------------------------------------------------------
// Phase 3: 8 blocks; block p exclusively reduces its 200 partials into out[p]
// (global scale factor applied here once). No atomics anywhere.
// ---------------------------------------------------------------------------
__global__ __launch_bounds__(256) void reduce_kernel(
    const float* __restrict__ partials,       // (P, RED_PER_P)
    const float* __restrict__ global_params,  // (1, 3)
    float*       __restrict__ out)            // (P,)
{
    __shared__ float s_red[4];
    const int p = blockIdx.x;
    float acc = 0.f;
    for (int i = threadIdx.x; i < RED_PER_P; i += 256)
        acc += partials[p * RED_PER_P + i];
    #pragma unroll
    for (int off = 32; off; off >>= 1)
        acc += __shfl_down(acc, off, 64);
    if ((threadIdx.x & 63) == 0)
        s_red[threadIdx.x >> 6] = acc;
    __syncthreads();
    if (threadIdx.x == 0)
        out[p] = global_params[0] * (s_red[0] + s_red[1] + s_red[2] + s_red[3]);
}

extern "C" void kernel_launch(void* const* d_in, const int* in_sizes, int n_in,
                              void* d_out, int out_size, void* d_ws, size_t ws_size,
                              hipStream_t stream) {
    const float* coords        = (const float*)d_in[0];
    const float* pair_params   = (const float*)d_in[1];
    const float* pair_poly     = (const float*)d_in[2];
    const float* global_params = (const float*)d_in[3];
    const int*   block_type    = (const int*)d_in[4];
    const int*   min_bond_sep  = (const int*)d_in[5];
    const int*   n_donH        = (const int*)d_in[6];
    const int*   donH_inds     = (const int*)d_in[7];
    const int*   donH_type     = (const int*)d_in[8];
    const int*   n_acc         = (const int*)d_in[9];
    const int*   acc_inds      = (const int*)d_in[10];
    const int*   acc_type      = (const int*)d_in[11];
    float* out = (float*)d_out;

    // Workspace layout (~337 KB)
    float4* wdon     = (float4*)d_ws;               // PB*MD*16 B = 160 KB
    float4* wacc     = wdon + PB * MD;              // PB*MA*16 B = 160 KB
    int2*   wcnt     = (int2*)(wacc + PB * MA);     // PB*8 B     = 10 KB
    float*  partials = (float*)(wcnt + PB);         // NBLK_SC*4 B = 6.4 KB

    pack_kernel<<<(PB * 16) / 256, 256, 0, stream>>>(
        coords, block_type, n_donH, donH_inds, donH_type,
        n_acc, acc_inds, acc_type, wdon, wacc, wcnt);

    score_kernel<<<NBLK_SC, 256, 0, stream>>>(
        wdon, wacc, wcnt, min_bond_sep,
        pair_params, pair_poly, partials);

    reduce_kernel<<<P, 256, 0, stream>>>(partials, global_params, out);
}